// Round 3
// baseline (3454.749 us; speedup 1.0000x reference)
//
#include <hip/hip_runtime.h>

#define HIDDEN 4096
#define INTER 14336
#define NTOK 8192   // B*S = 4*2048

typedef _Float16 half8 __attribute__((ext_vector_type(8)));
typedef float floatx4 __attribute__((ext_vector_type(4)));

#define AS1C(p) ((const __attribute__((address_space(1))) void*)(p))
#define AS3(p)  ((__attribute__((address_space(3))) void*)(p))
#define BAR()   asm volatile("s_barrier" ::: "memory")

// ---------------- conversion kernels ----------------

__global__ void cvt_w_kernel(const int* __restrict__ src, _Float16* __restrict__ dst, long n) {
    long i0 = ((long)blockIdx.x * blockDim.x + threadIdx.x) * 8;
    long stride = (long)gridDim.x * blockDim.x * 8;
    for (long i = i0; i < n; i += stride) {
        int4 a = *(const int4*)(src + i);
        int4 b = *(const int4*)(src + i + 4);
        half8 h;
        h[0] = (_Float16)a.x; h[1] = (_Float16)a.y; h[2] = (_Float16)a.z; h[3] = (_Float16)a.w;
        h[4] = (_Float16)b.x; h[5] = (_Float16)b.y; h[6] = (_Float16)b.z; h[7] = (_Float16)b.w;
        *(half8*)(dst + i) = h;
    }
}

__global__ void cvt_x_kernel(const float* __restrict__ src, _Float16* __restrict__ dst, long n) {
    long i0 = ((long)blockIdx.x * blockDim.x + threadIdx.x) * 8;
    long stride = (long)gridDim.x * blockDim.x * 8;
    for (long i = i0; i < n; i += stride) {
        float4 a = *(const float4*)(src + i);
        float4 b = *(const float4*)(src + i + 4);
        half8 h;
        h[0] = (_Float16)a.x; h[1] = (_Float16)a.y; h[2] = (_Float16)a.z; h[3] = (_Float16)a.w;
        h[4] = (_Float16)b.x; h[5] = (_Float16)b.y; h[6] = (_Float16)b.z; h[7] = (_Float16)b.w;
        *(half8*)(dst + i) = h;
    }
}

// ---------------- 256x256 barrier-light GEMM ----------------
// C[m,n] = sum_k A[m,k]*B[n,k], both K-major. BM=BN=256, BK=64, 512 thr (8 waves 2x4).
// Per-wave output 128x64 = 8x4 frags of 16x16x32. LDS 128KB: 2 x (A 32KB + B 32KB).
// Tile body is BARRIER-FREE (stable buffer): compiler pipelines ds_read||MFMA.
// Per-tile boundary: BAR -> stage(t+2 into cur) -> vmcnt(8) [waits only t+1] -> BAR.
// T2 swizzle: 16B slot ^= (row&7) on global SRC (staging) + ds_read addr (row&7==lane&7).
// MODE 0: gate -> fp16 g*scale. MODE 1: up -> h=silu(g)*u in-place. MODE 2: down -> fp32.

template<int KDIM, int NBN, int MODE>
__global__ __launch_bounds__(512, 2) void gemm8p(
        const _Float16* __restrict__ Aptr, const _Float16* __restrict__ Bptr,
        const float* __restrict__ scale, const _Float16* gbuf, void* outp)
{
    constexpr int NT = KDIM / 64;
    __shared__ _Float16 sA[2][256 * 64];
    __shared__ _Float16 sB[2][256 * 64];

    const int tid  = threadIdx.x;
    const int lane = tid & 63;
    const int wid  = tid >> 6;
    const int wr   = wid >> 2;   // 0..1
    const int wc   = wid & 3;    // 0..3

    // T1: bijective XCD swizzle (grid % 8 == 0 for all our launches)
    const int nwg = gridDim.x;
    const int bid = blockIdx.x;
    const int swz = (bid & 7) * (nwg >> 3) + (bid >> 3);
    const int bm = swz / NBN;
    const int bn = swz % NBN;
    const long rowA0 = (long)bm * 256;
    const long rowB0 = (long)bn * 256;

    // ---- staging addresses (per-thread constants) ----
    const int srow  = tid >> 3;                    // 0..63 (row within 64-row pass)
    const int sslot = (tid & 7) ^ (srow & 7);      // pre-swizzled global 16B slot
    const _Float16* gA = Aptr + (rowA0 + srow) * (long)KDIM + sslot * 8;
    const _Float16* gB = Bptr + (rowB0 + srow) * (long)KDIM + sslot * 8;

    auto STAGE = [&](int t) {                      // full tile t -> buf[t&1] (8 loads)
        _Float16* dA = &sA[t & 1][tid * 8];
        _Float16* dB = &sB[t & 1][tid * 8];
        const _Float16* sa = gA + (long)t * 64;
        const _Float16* sb = gB + (long)t * 64;
#pragma unroll
        for (int p = 0; p < 4; ++p) {
            __builtin_amdgcn_global_load_lds(AS1C(sa + p * 64 * (long)KDIM), AS3(dA + p * 4096), 16, 0, 0);
            __builtin_amdgcn_global_load_lds(AS1C(sb + p * 64 * (long)KDIM), AS3(dB + p * 4096), 16, 0, 0);
        }
    };

    // ---- ds_read offsets (elements), row&7 == lane&7 for all frags ----
    const int arow = wr * 128 + (lane & 15);
    const int brow = wc * 64  + (lane & 15);
    const int s0 = (lane >> 4) ^ (lane & 7);         // khalf 0 slot
    const int s1 = (4 + (lane >> 4)) ^ (lane & 7);   // khalf 1 slot
    const int aoff0 = arow * 64 + s0 * 8;            // + m*1024
    const int aoff1 = arow * 64 + s1 * 8;
    const int boff0 = brow * 64 + s0 * 8;            // + n*1024
    const int boff1 = brow * 64 + s1 * 8;

    floatx4 acc[8][4] = {};

    // ---- prologue ----
    STAGE(0);
    STAGE(1);
    asm volatile("s_waitcnt vmcnt(8)" ::: "memory");   // tile0 landed (tile1's 8 in flight)
    BAR();

    for (int t = 0; t < NT; ++t) {
        const _Float16* Ac = &sA[t & 1][0];
        const _Float16* Bc = &sB[t & 1][0];

        half8 a0[4][2], a1[4][2], b0[2][2], b1[2][2];
#pragma unroll
        for (int m = 0; m < 4; ++m) {
            a0[m][0] = *(const half8*)(Ac + aoff0 + m * 1024);
            a0[m][1] = *(const half8*)(Ac + aoff1 + m * 1024);
        }
#pragma unroll
        for (int n = 0; n < 2; ++n) {
            b0[n][0] = *(const half8*)(Bc + boff0 + n * 1024);
            b0[n][1] = *(const half8*)(Bc + boff1 + n * 1024);
            b1[n][0] = *(const half8*)(Bc + boff0 + (2 + n) * 1024);
            b1[n][1] = *(const half8*)(Bc + boff1 + (2 + n) * 1024);
        }
        // Q0: m0-3 x n0-1
        __builtin_amdgcn_s_setprio(1);
#pragma unroll
        for (int m = 0; m < 4; ++m)
#pragma unroll
            for (int n = 0; n < 2; ++n) {
                acc[m][n] = __builtin_amdgcn_mfma_f32_16x16x32_f16(a0[m][0], b0[n][0], acc[m][n], 0, 0, 0);
                acc[m][n] = __builtin_amdgcn_mfma_f32_16x16x32_f16(a0[m][1], b0[n][1], acc[m][n], 0, 0, 0);
            }
        __builtin_amdgcn_s_setprio(0);
        // a4-7 reads (overlap with Q1 MFMA via compiler scheduling)
#pragma unroll
        for (int m = 0; m < 4; ++m) {
            a1[m][0] = *(const half8*)(Ac + aoff0 + (4 + m) * 1024);
            a1[m][1] = *(const half8*)(Ac + aoff1 + (4 + m) * 1024);
        }
        __builtin_amdgcn_s_setprio(1);
        // Q1: m0-3 x n2-3
#pragma unroll
        for (int m = 0; m < 4; ++m)
#pragma unroll
            for (int n = 0; n < 2; ++n) {
                acc[m][2 + n] = __builtin_amdgcn_mfma_f32_16x16x32_f16(a0[m][0], b1[n][0], acc[m][2 + n], 0, 0, 0);
                acc[m][2 + n] = __builtin_amdgcn_mfma_f32_16x16x32_f16(a0[m][1], b1[n][1], acc[m][2 + n], 0, 0, 0);
            }
        // Q2: m4-7 x n2-3
#pragma unroll
        for (int m = 0; m < 4; ++m)
#pragma unroll
            for (int n = 0; n < 2; ++n) {
                acc[4 + m][2 + n] = __builtin_amdgcn_mfma_f32_16x16x32_f16(a1[m][0], b1[n][0], acc[4 + m][2 + n], 0, 0, 0);
                acc[4 + m][2 + n] = __builtin_amdgcn_mfma_f32_16x16x32_f16(a1[m][1], b1[n][1], acc[4 + m][2 + n], 0, 0, 0);
            }
        // Q3: m4-7 x n0-1
#pragma unroll
        for (int m = 0; m < 4; ++m)
#pragma unroll
            for (int n = 0; n < 2; ++n) {
                acc[4 + m][n] = __builtin_amdgcn_mfma_f32_16x16x32_f16(a1[m][0], b0[n][0], acc[4 + m][n], 0, 0, 0);
                acc[4 + m][n] = __builtin_amdgcn_mfma_f32_16x16x32_f16(a1[m][1], b0[n][1], acc[4 + m][n], 0, 0, 0);
            }
        __builtin_amdgcn_s_setprio(0);

        // ---- boundary: cur fully consumed -> refill cur with t+2 ----
        if (t + 1 < NT) {
            BAR();                               // all waves done reading buf[t&1]
            if (t + 2 < NT) {
                STAGE(t + 2);                    // into buf[t&1]
                asm volatile("s_waitcnt vmcnt(8)" ::: "memory");  // t+1's 8 landed
            } else {
                asm volatile("s_waitcnt vmcnt(0)" ::: "memory");
            }
            BAR();                               // buf[(t+1)&1] ready for all
        }
    }

    // ---- epilogue ----
    const int orow = bm * 256 + wr * 128 + ((lane >> 4) * 4);
    const int ocol = bn * 256 + wc * 64 + (lane & 15);
#pragma unroll
    for (int n = 0; n < 4; ++n) {
        const int col = ocol + n * 16;
        const float sc = scale[col];
#pragma unroll
        for (int m = 0; m < 8; ++m) {
            const int row = orow + m * 16;
#pragma unroll
            for (int q = 0; q < 4; ++q) {
                if (MODE == 0) {
                    _Float16* G = (_Float16*)outp;
                    G[(long)(row + q) * INTER + col] = (_Float16)(acc[m][n][q] * sc);
                } else if (MODE == 1) {
                    _Float16* H = (_Float16*)outp;   // == gbuf, in-place
                    const long idx = (long)(row + q) * INTER + col;
                    const float g = (float)gbuf[idx];
                    const float u = acc[m][n][q] * sc;
                    H[idx] = (_Float16)(g / (1.0f + __expf(-g)) * u);
                } else {
                    float* O = (float*)outp;
                    O[(long)(row + q) * HIDDEN + col] = acc[m][n][q] * sc;
                }
            }
        }
    }
}

// ---------------- launch ----------------

extern "C" void kernel_launch(void* const* d_in, const int* in_sizes, int n_in,
                              void* d_out, int out_size, void* d_ws, size_t ws_size,
                              hipStream_t stream) {
    const float* x   = (const float*)d_in[0];
    const int*   gw  = (const int*)d_in[1];
    const float* gsc = (const float*)d_in[2];
    const int*   uw  = (const int*)d_in[3];
    const float* usc = (const float*)d_in[4];
    const int*   dw  = (const int*)d_in[5];
    const float* dsc = (const float*)d_in[6];
    float* out = (float*)d_out;

    char* ws = (char*)d_ws;
    _Float16* x16  = (_Float16*)(ws);                    //  64 MiB
    _Float16* wg16 = (_Float16*)(ws + 67108864ll);       // 112 MiB
    _Float16* wu16 = (_Float16*)(ws + 184549376ll);      // 112 MiB
    _Float16* wd16 = (_Float16*)(ws + 301989888ll);      // 112 MiB
    _Float16* gh16 = (_Float16*)(ws + 419430400ll);      // 224 MiB (g, then h in-place)

    cvt_x_kernel<<<4096, 256, 0, stream>>>(x,  x16,  (long)NTOK * HIDDEN);
    cvt_w_kernel<<<4096, 256, 0, stream>>>(gw, wg16, (long)INTER * HIDDEN);
    cvt_w_kernel<<<4096, 256, 0, stream>>>(uw, wu16, (long)INTER * HIDDEN);
    cvt_w_kernel<<<4096, 256, 0, stream>>>(dw, wd16, (long)HIDDEN * INTER);

    // gate: [8192 x 14336] = X * Wg^T, write g16
    gemm8p<HIDDEN, 56, 0><<<(NTOK / 256) * (INTER / 256), 512, 0, stream>>>(
        x16, wg16, gsc, nullptr, gh16);
    // up: same shape, epilogue h = silu(g) * u, in-place over gh16
    gemm8p<HIDDEN, 56, 1><<<(NTOK / 256) * (INTER / 256), 512, 0, stream>>>(
        x16, wu16, usc, gh16, gh16);
    // down: [8192 x 4096] = H * Wd^T, fp32 out
    gemm8p<INTER, 16, 2><<<(NTOK / 256) * (HIDDEN / 256), 512, 0, stream>>>(
        gh16, wd16, dsc, nullptr, out);
}

// Round 4
// 3004.672 us; speedup vs baseline: 1.1498x; 1.1498x over previous
//
#include <hip/hip_runtime.h>

#define HIDDEN 4096
#define INTER 14336
#define NTOK 8192   // B*S = 4*2048

typedef _Float16 half8 __attribute__((ext_vector_type(8)));
typedef float floatx4 __attribute__((ext_vector_type(4)));

#define AS1C(p) ((const __attribute__((address_space(1))) void*)(p))
#define AS3(p)  ((__attribute__((address_space(3))) void*)(p))
#define SBAR()  __builtin_amdgcn_s_barrier()
#define WAIT_VM0() asm volatile("s_waitcnt vmcnt(0)" ::: "memory")
#define PRIO(x) __builtin_amdgcn_s_setprio(x)
#define MFMA16(A,B,C) __builtin_amdgcn_mfma_f32_16x16x32_f16(A,B,C,0,0,0)

// ---------------- conversion kernels ----------------

__global__ void cvt_w_kernel(const int* __restrict__ src, _Float16* __restrict__ dst, long n) {
    long i0 = ((long)blockIdx.x * blockDim.x + threadIdx.x) * 8;
    long stride = (long)gridDim.x * blockDim.x * 8;
    for (long i = i0; i < n; i += stride) {
        int4 a = *(const int4*)(src + i);
        int4 b = *(const int4*)(src + i + 4);
        half8 h;
        h[0] = (_Float16)a.x; h[1] = (_Float16)a.y; h[2] = (_Float16)a.z; h[3] = (_Float16)a.w;
        h[4] = (_Float16)b.x; h[5] = (_Float16)b.y; h[6] = (_Float16)b.z; h[7] = (_Float16)b.w;
        *(half8*)(dst + i) = h;
    }
}

__global__ void cvt_x_kernel(const float* __restrict__ src, _Float16* __restrict__ dst, long n) {
    long i0 = ((long)blockIdx.x * blockDim.x + threadIdx.x) * 8;
    long stride = (long)gridDim.x * blockDim.x * 8;
    for (long i = i0; i < n; i += stride) {
        float4 a = *(const float4*)(src + i);
        float4 b = *(const float4*)(src + i + 4);
        half8 h;
        h[0] = (_Float16)a.x; h[1] = (_Float16)a.y; h[2] = (_Float16)a.z; h[3] = (_Float16)a.w;
        h[4] = (_Float16)b.x; h[5] = (_Float16)b.y; h[6] = (_Float16)b.z; h[7] = (_Float16)b.w;
        *(half8*)(dst + i) = h;
    }
}

// ---------------- fused gate+up (m201-style 4-phase) ----------------
// C[m,n] = sum_k X[m,k]*W[n,k]. BM=256, BN=128, BK=64, 512 thr (8 waves, 2M x 4N).
// Per-wave: 128 rows x 32 cols per matrix; acc 8m x 2n x {g,u}.
// LDS 128KB: 2buf x (A 32KB + Bg 16KB + Bu 16KB).
// Phase cadence per K-tile: P0 g(m0-3), P1 g(m4-7), P2 u(m0-3), P3 u(m4-7).
// Prefetch of t+1 (into dead buffer): P0->A-h0, P1->A-h1, P2->Bg+Bu.
// One vmcnt(0)+barrier per tile at the boundary (all issues >=2 phases old).

__global__ __launch_bounds__(512, 2) void gateup_kernel(
        const _Float16* __restrict__ Aptr, const _Float16* __restrict__ Bgp,
        const _Float16* __restrict__ Bup, const float* __restrict__ gsc,
        const float* __restrict__ usc, _Float16* __restrict__ H)
{
    constexpr int KDIM = HIDDEN;
    constexpr int NT = KDIM / 64;      // 64
    constexpr int NBN = INTER / 128;   // 112
    __shared__ _Float16 sA[2][256 * 64];
    __shared__ _Float16 sG[2][128 * 64];
    __shared__ _Float16 sU[2][128 * 64];

    const int tid  = threadIdx.x;
    const int lane = tid & 63;
    const int wid  = tid >> 6;
    const int wr   = wid >> 2;   // 0..1
    const int wc   = wid & 3;    // 0..3

    const int nwg = gridDim.x;
    const int bid = blockIdx.x;
    const int swz = (bid & 7) * (nwg >> 3) + (bid >> 3);
    const int bm = swz / NBN;
    const int bn = swz % NBN;

    // staging addresses (T2: pre-swizzled global source slot)
    const int srow  = tid >> 3;                  // 0..63
    const int sslot = (tid & 7) ^ (srow & 7);
    const _Float16* gA = Aptr + ((long)bm * 256 + srow) * KDIM + sslot * 8;
    const _Float16* gG = Bgp + ((long)bn * 128 + srow) * KDIM + sslot * 8;
    const _Float16* gU = Bup + ((long)bn * 128 + srow) * KDIM + sslot * 8;

    auto stageA = [&](int t, int half) {   // 16KB half-tile, 2 loads/thread
        _Float16* d = &sA[t & 1][half * 8192 + tid * 8];
        const _Float16* s = gA + (long)half * 128 * KDIM + (long)t * 64;
        __builtin_amdgcn_global_load_lds(AS1C(s), AS3(d), 16, 0, 0);
        __builtin_amdgcn_global_load_lds(AS1C(s + 64 * KDIM), AS3(d + 4096), 16, 0, 0);
    };
    auto stageG = [&](int t) {
        _Float16* d = &sG[t & 1][tid * 8];
        const _Float16* s = gG + (long)t * 64;
        __builtin_amdgcn_global_load_lds(AS1C(s), AS3(d), 16, 0, 0);
        __builtin_amdgcn_global_load_lds(AS1C(s + 64 * KDIM), AS3(d + 4096), 16, 0, 0);
    };
    auto stageU = [&](int t) {
        _Float16* d = &sU[t & 1][tid * 8];
        const _Float16* s = gU + (long)t * 64;
        __builtin_amdgcn_global_load_lds(AS1C(s), AS3(d), 16, 0, 0);
        __builtin_amdgcn_global_load_lds(AS1C(s + 64 * KDIM), AS3(d + 4096), 16, 0, 0);
    };

    // ds_read fragment offsets (elements); row&7 == lane&7 for all frags
    const int arow = wr * 128 + (lane & 15);
    const int brow = wc * 32  + (lane & 15);
    const int sl0 = ((lane >> 4) ^ (lane & 7)) * 8;
    const int sl1 = ((4 + (lane >> 4)) ^ (lane & 7)) * 8;
    const int aof0 = arow * 64 + sl0, aof1 = arow * 64 + sl1;
    const int bof0 = brow * 64 + sl0, bof1 = brow * 64 + sl1;

    floatx4 ag[8][2] = {};
    floatx4 au[8][2] = {};
    half8 a[8][2], bg[2][2], bu[2][2];

    // prologue: tile 0
    stageA(0, 0); stageA(0, 1); stageG(0); stageU(0);
    WAIT_VM0();
    SBAR();

    for (int t = 0; t < NT; ++t) {
        const _Float16* A = &sA[t & 1][0];
        const _Float16* G = &sG[t & 1][0];
        const _Float16* U = &sU[t & 1][0];
        const bool st = (t + 1 < NT);

        // ---- P0: g, m0-3 ----
#pragma unroll
        for (int m = 0; m < 4; ++m) {
            a[m][0] = *(const half8*)(A + aof0 + m * 1024);
            a[m][1] = *(const half8*)(A + aof1 + m * 1024);
        }
#pragma unroll
        for (int n = 0; n < 2; ++n) {
            bg[n][0] = *(const half8*)(G + bof0 + n * 1024);
            bg[n][1] = *(const half8*)(G + bof1 + n * 1024);
        }
        if (st) stageA(t + 1, 0);
        SBAR();
        PRIO(1);
#pragma unroll
        for (int m = 0; m < 4; ++m)
#pragma unroll
            for (int n = 0; n < 2; ++n) {
                ag[m][n] = MFMA16(a[m][0], bg[n][0], ag[m][n]);
                ag[m][n] = MFMA16(a[m][1], bg[n][1], ag[m][n]);
            }
        PRIO(0);
        SBAR();

        // ---- P1: g, m4-7 ----
#pragma unroll
        for (int m = 4; m < 8; ++m) {
            a[m][0] = *(const half8*)(A + aof0 + m * 1024);
            a[m][1] = *(const half8*)(A + aof1 + m * 1024);
        }
        if (st) stageA(t + 1, 1);
        SBAR();
        PRIO(1);
#pragma unroll
        for (int m = 4; m < 8; ++m)
#pragma unroll
            for (int n = 0; n < 2; ++n) {
                ag[m][n] = MFMA16(a[m][0], bg[n][0], ag[m][n]);
                ag[m][n] = MFMA16(a[m][1], bg[n][1], ag[m][n]);
            }
        PRIO(0);
        SBAR();

        // ---- P2: u, m0-3 ----
#pragma unroll
        for (int n = 0; n < 2; ++n) {
            bu[n][0] = *(const half8*)(U + bof0 + n * 1024);
            bu[n][1] = *(const half8*)(U + bof1 + n * 1024);
        }
        if (st) { stageG(t + 1); stageU(t + 1); }
        SBAR();
        PRIO(1);
#pragma unroll
        for (int m = 0; m < 4; ++m)
#pragma unroll
            for (int n = 0; n < 2; ++n) {
                au[m][n] = MFMA16(a[m][0], bu[n][0], au[m][n]);
                au[m][n] = MFMA16(a[m][1], bu[n][1], au[m][n]);
            }
        PRIO(0);
        SBAR();

        // ---- P3: u, m4-7; tile boundary ----
        PRIO(1);
#pragma unroll
        for (int m = 4; m < 8; ++m)
#pragma unroll
            for (int n = 0; n < 2; ++n) {
                au[m][n] = MFMA16(a[m][0], bu[n][0], au[m][n]);
                au[m][n] = MFMA16(a[m][1], bu[n][1], au[m][n]);
            }
        PRIO(0);
        WAIT_VM0();   // t+1's 8 loads: oldest 4 phases, newest 2 phases old
        SBAR();
    }

    // ---- epilogue: h = silu(g*gs) * (u*us), fp16 ----
    const int orow = bm * 256 + wr * 128 + ((lane >> 4) * 4);
    const int ocol = bn * 128 + wc * 32 + (lane & 15);
#pragma unroll
    for (int n = 0; n < 2; ++n) {
        const int col = ocol + n * 16;
        const float gs = gsc[col];
        const float us = usc[col];
#pragma unroll
        for (int m = 0; m < 8; ++m) {
            const int row = orow + m * 16;
#pragma unroll
            for (int q = 0; q < 4; ++q) {
                const float g = ag[m][n][q] * gs;
                const float u = au[m][n][q] * us;
                H[(long)(row + q) * INTER + col] = (_Float16)(g / (1.0f + __expf(-g)) * u);
            }
        }
    }
}

// ---------------- down GEMM (m201-style 4-phase, 256x256) ----------------
// Phases: P0 m0-3 x n0-1 (reads A0-3, B0-1), P1 m0-3 x n2-3 (B2-3),
// P2 m4-7 x n2-3 (A4-7), P3 m4-7 x n0-1. Prefetch: P0->A-h0, P1->A-h1, P2->B-h0+h1.

__global__ __launch_bounds__(512, 2) void down_kernel(
        const _Float16* __restrict__ Aptr, const _Float16* __restrict__ Bptr,
        const float* __restrict__ dsc, float* __restrict__ out)
{
    constexpr int KDIM = INTER;
    constexpr int NT = KDIM / 64;     // 224
    constexpr int NBN = HIDDEN / 256; // 16
    __shared__ _Float16 sA[2][256 * 64];
    __shared__ _Float16 sB[2][256 * 64];

    const int tid  = threadIdx.x;
    const int lane = tid & 63;
    const int wid  = tid >> 6;
    const int wr   = wid >> 2;
    const int wc   = wid & 3;

    const int nwg = gridDim.x;
    const int bid = blockIdx.x;
    const int swz = (bid & 7) * (nwg >> 3) + (bid >> 3);
    const int bm = swz / NBN;
    const int bn = swz % NBN;

    const int srow  = tid >> 3;
    const int sslot = (tid & 7) ^ (srow & 7);
    const _Float16* gA = Aptr + ((long)bm * 256 + srow) * KDIM + sslot * 8;
    const _Float16* gB = Bptr + ((long)bn * 256 + srow) * KDIM + sslot * 8;

    auto stageA = [&](int t, int half) {
        _Float16* d = &sA[t & 1][half * 8192 + tid * 8];
        const _Float16* s = gA + (long)half * 128 * KDIM + (long)t * 64;
        __builtin_amdgcn_global_load_lds(AS1C(s), AS3(d), 16, 0, 0);
        __builtin_amdgcn_global_load_lds(AS1C(s + 64 * KDIM), AS3(d + 4096), 16, 0, 0);
    };
    auto stageB = [&](int t, int half) {
        _Float16* d = &sB[t & 1][half * 8192 + tid * 8];
        const _Float16* s = gB + (long)half * 128 * KDIM + (long)t * 64;
        __builtin_amdgcn_global_load_lds(AS1C(s), AS3(d), 16, 0, 0);
        __builtin_amdgcn_global_load_lds(AS1C(s + 64 * KDIM), AS3(d + 4096), 16, 0, 0);
    };

    const int arow = wr * 128 + (lane & 15);
    const int brow = wc * 64  + (lane & 15);
    const int sl0 = ((lane >> 4) ^ (lane & 7)) * 8;
    const int sl1 = ((4 + (lane >> 4)) ^ (lane & 7)) * 8;
    const int aof0 = arow * 64 + sl0, aof1 = arow * 64 + sl1;
    const int bof0 = brow * 64 + sl0, bof1 = brow * 64 + sl1;

    floatx4 acc[8][4] = {};
    half8 a[8][2], b[4][2];

    stageA(0, 0); stageA(0, 1); stageB(0, 0); stageB(0, 1);
    WAIT_VM0();
    SBAR();

    for (int t = 0; t < NT; ++t) {
        const _Float16* A = &sA[t & 1][0];
        const _Float16* B = &sB[t & 1][0];
        const bool st = (t + 1 < NT);

        // ---- P0: m0-3 x n0-1 ----
#pragma unroll
        for (int m = 0; m < 4; ++m) {
            a[m][0] = *(const half8*)(A + aof0 + m * 1024);
            a[m][1] = *(const half8*)(A + aof1 + m * 1024);
        }
#pragma unroll
        for (int n = 0; n < 2; ++n) {
            b[n][0] = *(const half8*)(B + bof0 + n * 1024);
            b[n][1] = *(const half8*)(B + bof1 + n * 1024);
        }
        if (st) stageA(t + 1, 0);
        SBAR();
        PRIO(1);
#pragma unroll
        for (int m = 0; m < 4; ++m)
#pragma unroll
            for (int n = 0; n < 2; ++n) {
                acc[m][n] = MFMA16(a[m][0], b[n][0], acc[m][n]);
                acc[m][n] = MFMA16(a[m][1], b[n][1], acc[m][n]);
            }
        PRIO(0);
        SBAR();

        // ---- P1: m0-3 x n2-3 ----
#pragma unroll
        for (int n = 2; n < 4; ++n) {
            b[n][0] = *(const half8*)(B + bof0 + n * 1024);
            b[n][1] = *(const half8*)(B + bof1 + n * 1024);
        }
        if (st) stageA(t + 1, 1);
        SBAR();
        PRIO(1);
#pragma unroll
        for (int m = 0; m < 4; ++m)
#pragma unroll
            for (int n = 2; n < 4; ++n) {
                acc[m][n] = MFMA16(a[m][0], b[n][0], acc[m][n]);
                acc[m][n] = MFMA16(a[m][1], b[n][1], acc[m][n]);
            }
        PRIO(0);
        SBAR();

        // ---- P2: m4-7 x n2-3 ----
#pragma unroll
        for (int m = 4; m < 8; ++m) {
            a[m][0] = *(const half8*)(A + aof0 + m * 1024);
            a[m][1] = *(const half8*)(A + aof1 + m * 1024);
        }
        if (st) { stageB(t + 1, 0); stageB(t + 1, 1); }
        SBAR();
        PRIO(1);
#pragma unroll
        for (int m = 4; m < 8; ++m)
#pragma unroll
            for (int n = 2; n < 4; ++n) {
                acc[m][n] = MFMA16(a[m][0], b[n][0], acc[m][n]);
                acc[m][n] = MFMA16(a[m][1], b[n][1], acc[m][n]);
            }
        PRIO(0);
        SBAR();

        // ---- P3: m4-7 x n0-1; boundary ----
        PRIO(1);
#pragma unroll
        for (int m = 4; m < 8; ++m)
#pragma unroll
            for (int n = 0; n < 2; ++n) {
                acc[m][n] = MFMA16(a[m][0], b[n][0], acc[m][n]);
                acc[m][n] = MFMA16(a[m][1], b[n][1], acc[m][n]);
            }
        PRIO(0);
        WAIT_VM0();
        SBAR();
    }

    const int orow = bm * 256 + wr * 128 + ((lane >> 4) * 4);
    const int ocol = bn * 256 + wc * 64 + (lane & 15);
#pragma unroll
    for (int n = 0; n < 4; ++n) {
        const int col = ocol + n * 16;
        const float sc = dsc[col];
#pragma unroll
        for (int m = 0; m < 8; ++m) {
            const int row = orow + m * 16;
#pragma unroll
            for (int q = 0; q < 4; ++q)
                out[(long)(row + q) * HIDDEN + col] = acc[m][n][q] * sc;
        }
    }
}

// ---------------- launch ----------------

extern "C" void kernel_launch(void* const* d_in, const int* in_sizes, int n_in,
                              void* d_out, int out_size, void* d_ws, size_t ws_size,
                              hipStream_t stream) {
    const float* x   = (const float*)d_in[0];
    const int*   gw  = (const int*)d_in[1];
    const float* gsc = (const float*)d_in[2];
    const int*   uw  = (const int*)d_in[3];
    const float* usc = (const float*)d_in[4];
    const int*   dw  = (const int*)d_in[5];
    const float* dsc = (const float*)d_in[6];
    float* out = (float*)d_out;

    char* ws = (char*)d_ws;
    _Float16* x16  = (_Float16*)(ws);                    //  64 MiB
    _Float16* wg16 = (_Float16*)(ws + 67108864ll);       // 112 MiB
    _Float16* wu16 = (_Float16*)(ws + 184549376ll);      // 112 MiB
    _Float16* wd16 = (_Float16*)(ws + 301989888ll);      // 112 MiB
    _Float16* h16  = (_Float16*)(ws + 419430400ll);      // 224 MiB

    cvt_x_kernel<<<4096, 256, 0, stream>>>(x,  x16,  (long)NTOK * HIDDEN);
    cvt_w_kernel<<<4096, 256, 0, stream>>>(gw, wg16, (long)INTER * HIDDEN);
    cvt_w_kernel<<<4096, 256, 0, stream>>>(uw, wu16, (long)INTER * HIDDEN);
    cvt_w_kernel<<<4096, 256, 0, stream>>>(dw, wd16, (long)HIDDEN * INTER);

    // fused gate+up+SwiGLU: [8192 x 14336], h fp16
    gateup_kernel<<<(NTOK / 256) * (INTER / 128), 512, 0, stream>>>(
        x16, wg16, wu16, gsc, usc, h16);
    // down: [8192 x 4096] = H * Wd^T, fp32 out
    down_kernel<<<(NTOK / 256) * (HIDDEN / 256), 512, 0, stream>>>(
        h16, wd16, dsc, out);
}